// Round 4
// baseline (242.265 us; speedup 1.0000x reference)
//
#include <hip/hip_runtime.h>
#include <math.h>

#define BB 8
#define DD 128
#define KK 256
#define XYZ 32768
#define EPSV 1e-5f

// ws layout (float offsets)
#define WS_X     0                     // [B*32, 256] = 65536
#define WS_Y     65536
#define WS_Z     131072
#define WS_RAW   196608                // [B,H,XYZ] = 524288
#define WS_SM    (WS_RAW + 524288)     // [B*32, 4] partial (m0,l0,m1,l1) = 1024
#define WS_PART  (WS_SM + 1024)        // [B,32,256] logit partials = 65536

// swizzled LDS index for proj tiles: row-major [32][256] with 16B-granule XOR
#define SWZ(row, kk) ((row) * 256 + (((((kk) >> 2) ^ ((row) & 7)) << 2) | ((kk) & 3)))

#define NRM4(s, a) { s += (a).x*(a).x + (a).y*(a).y + (a).z*(a).z + (a).w*(a).w; }
#define DOT4(s, a, b) { s = fmaf((a).x,(b).x, fmaf((a).y,(b).y, fmaf((a).z,(b).z, fmaf((a).w,(b).w,(s))))); }

// ---------------- fused projections + raw scores -----------------
// grid 256 x 512: one block per (b,x).
// Phase A: block recomputes y/z projections for its b (redundant across the
//          32 x-blocks — ~3.4us VALU/CU, cheaper than a kernel round-trip),
//          plus its own x-row. Results go straight to LDS (swizzled).
//          xx==0 block also stores y/z proj to ws for the logits kernel.
// Phase B: round-2 score loop + per-(b,x) softmax partials.
__global__ void __launch_bounds__(512)
tan_projscore_kernel(const float* __restrict__ x, const float* __restrict__ y,
                     const float* __restrict__ z,
                     const float* __restrict__ Vx, const float* __restrict__ Vy,
                     const float* __restrict__ Vz,
                     const float* __restrict__ gx, const float* __restrict__ gy,
                     const float* __restrict__ gz,
                     const float* __restrict__ bx, const float* __restrict__ by,
                     const float* __restrict__ bz,
                     const float* __restrict__ Vh, const float* __restrict__ gh,
                     const float* __restrict__ bh, float* __restrict__ ws) {
    __shared__ float ys[32 * 256];
    __shared__ float zs[32 * 256];
    __shared__ float xsh[256];
    __shared__ float nred[16];
    __shared__ float smred[8][4];
    __shared__ float shh;
    int t = threadIdx.x;
    int bb = blockIdx.x >> 5;
    int xx = blockIdx.x & 31;
    int k = t & 255;
    int half = __builtin_amdgcn_readfirstlane(t >> 8);   // wave-uniform

    // Vh Frobenius norm (wave 0)
    if (t < 64) {
        float4 h1 = *(const float4*)(Vh + t * 8);
        float4 h2 = *(const float4*)(Vh + t * 8 + 4);
        float hs = h1.x * h1.x + h1.y * h1.y + h1.z * h1.z + h1.w * h1.w
                 + h2.x * h2.x + h2.y * h2.y + h2.z * h2.z + h2.w * h2.w;
#pragma unroll
        for (int o = 32; o > 0; o >>= 1) hs += __shfl_xor(hs, o);
        if (t == 0) shh = hs;
    }

    // ---- phase A: projections ----
    // half 0: y-proj (32 rows) + x-proj (own row); half 1: z-proj (32 rows)
    const float* inp  = half ? (z + bb * 32 * DD) : (y + bb * 32 * DD);
    const float* V    = half ? Vz : Vy;
    const float* bias = half ? bz : by;
    const float* gg   = half ? gz : gy;
    const float4* v4  = (const float4*)(V + k * DD);

    float acc[32];
#pragma unroll
    for (int r = 0; r < 32; ++r) acc[r] = 0.f;
    float ssp = 0.f;

#pragma unroll
    for (int dg = 0; dg < 8; ++dg) {
        float4 a0 = v4[dg * 4 + 0];
        float4 a1 = v4[dg * 4 + 1];
        float4 a2 = v4[dg * 4 + 2];
        float4 a3 = v4[dg * 4 + 3];
        NRM4(ssp, a0) NRM4(ssp, a1) NRM4(ssp, a2) NRM4(ssp, a3)
#pragma unroll
        for (int r = 0; r < 32; ++r) {
            const float4* bp = (const float4*)(inp + r * DD + dg * 16);  // uniform -> s_load
            float4 b0 = bp[0], b1 = bp[1], b2 = bp[2], b3 = bp[3];
            float s = acc[r];
            DOT4(s, a0, b0) DOT4(s, a1, b1) DOT4(s, a2, b2) DOT4(s, a3, b3)
            acc[r] = s;
        }
    }

    // x-proj on half 0
    float xacc = 0.f, ssxp = 0.f;
    if (half == 0) {
        const float4* vx4 = (const float4*)(Vx + k * DD);
        const float* xr = x + (bb * 32 + xx) * DD;                       // uniform
#pragma unroll
        for (int dg = 0; dg < 8; ++dg) {
            float4 a0 = vx4[dg * 4 + 0];
            float4 a1 = vx4[dg * 4 + 1];
            float4 a2 = vx4[dg * 4 + 2];
            float4 a3 = vx4[dg * 4 + 3];
            NRM4(ssxp, a0) NRM4(ssxp, a1) NRM4(ssxp, a2) NRM4(ssxp, a3)
            const float4* bp = (const float4*)(xr + dg * 16);
            float4 b0 = bp[0], b1 = bp[1], b2 = bp[2], b3 = bp[3];
            DOT4(xacc, a0, b0) DOT4(xacc, a1, b1) DOT4(xacc, a2, b2) DOT4(xacc, a3, b3)
        }
    }

    // block-local norm reductions (fixed order -> bit-identical across blocks)
    {
        float s1 = ssp, s2 = ssxp;
#pragma unroll
        for (int o = 32; o > 0; o >>= 1) {
            s1 += __shfl_xor(s1, o);
            s2 += __shfl_xor(s2, o);
        }
        int w = t >> 6;
        if ((t & 63) == 0) { nred[w * 2] = s1; nred[w * 2 + 1] = s2; }
    }
    __syncthreads();
    float ssY = nred[0] + nred[2] + nred[4] + nred[6];
    float ssX = nred[1] + nred[3] + nred[5] + nred[7];
    float ssZ = nred[8] + nred[10] + nred[12] + nred[14];

    {
        float scl = gg[0] * rsqrtf(half ? ssZ : ssY);
        float bv = bias[k];
        float* lbuf = half ? zs : ys;
        float* gbuf = ws + (half ? WS_Z : WS_Y) + bb * 8192;
        bool store_g = (xx == 0);
#pragma unroll
        for (int r = 0; r < 32; ++r) {
            float v = fmaxf(acc[r] * scl + bv, 0.f);
            lbuf[SWZ(r, k)] = v;
            if (store_g) gbuf[r * 256 + k] = v;
        }
        if (half == 0) {
            float xscl = gx[0] * rsqrtf(ssX);
            float xv = fmaxf(xacc * xscl + bx[k], 0.f);
            xsh[k] = xv;
            ws[WS_X + (bb * 32 + xx) * 256 + k] = xv;
        }
    }
    __syncthreads();

    // ---- phase B: score loop (round-2 structure) ----
    float sh = gh[0] * rsqrtf(shh);

    int ty = t >> 4;          // 0..31 : y
    int tz = t & 15;          // z0 = tz, z1 = tz+16
    int z0 = tz, z1 = tz + 16;
    int ysw = (ty & 7);
    int zsw = (tz & 7);       // (tz+16)&7 == tz&7

    float s00 = 0.f, s01 = 0.f, s10 = 0.f, s11 = 0.f;

#pragma unroll 4
    for (int kc = 0; kc < 256; kc += 4) {
        int g = kc >> 2;
        float4 xv  = *(const float4*)(xsh + kc);                 // uniform LDS broadcast
        float4 vh0 = *(const float4*)(Vh + kc);
        float4 vh1 = *(const float4*)(Vh + KK + kc);
        float4 ya = *(const float4*)(ys + ty * 256 + ((g ^ ysw) << 2));
        float4 za = *(const float4*)(zs + z0 * 256 + ((g ^ zsw) << 2));
        float4 zb = *(const float4*)(zs + z1 * 256 + ((g ^ zsw) << 2));
#define TAN_STEP(c) { \
        float xs = sh * xv.c; \
        float w0 = xs * vh0.c, w1 = xs * vh1.c; \
        float t0 = w0 * ya.c, t1 = w1 * ya.c; \
        s00 = fmaf(t0, za.c, s00); s01 = fmaf(t0, zb.c, s01); \
        s10 = fmaf(t1, za.c, s10); s11 = fmaf(t1, zb.c, s11); }
        TAN_STEP(x) TAN_STEP(y) TAN_STEP(z) TAN_STEP(w)
#undef TAN_STEP
    }

    float b0 = bh[0], b1 = bh[1];
    s00 += b0; s01 += b0;
    s10 += b1; s11 += b1;
    float* r0 = ws + WS_RAW + (bb * 2 + 0) * XYZ + xx * 1024;
    float* r1 = r0 + XYZ;
    r0[ty * 32 + z0] = s00;  r0[ty * 32 + z1] = s01;
    r1[ty * 32 + z0] = s10;  r1[ty * 32 + z1] = s11;

    // per-(b,x) online softmax partials
    float m0 = fmaxf(s00, s01);
    float l0 = __expf(s00 - m0) + __expf(s01 - m0);
    float m1 = fmaxf(s10, s11);
    float l1 = __expf(s10 - m1) + __expf(s11 - m1);
#pragma unroll
    for (int o = 1; o < 64; o <<= 1) {
        float mo = __shfl_xor(m0, o), lo = __shfl_xor(l0, o);
        float nm = fmaxf(m0, mo);
        l0 = l0 * __expf(m0 - nm) + lo * __expf(mo - nm); m0 = nm;
        mo = __shfl_xor(m1, o); lo = __shfl_xor(l1, o);
        nm = fmaxf(m1, mo);
        l1 = l1 * __expf(m1 - nm) + lo * __expf(mo - nm); m1 = nm;
    }
    if ((t & 63) == 0) {
        int w = t >> 6;
        smred[w][0] = m0; smred[w][1] = l0;
        smred[w][2] = m1; smred[w][3] = l1;
    }
    __syncthreads();
    if (t == 0) {
        float M0 = smred[0][0], L0 = smred[0][1];
        float M1 = smred[0][2], L1 = smred[0][3];
#pragma unroll
        for (int w = 1; w < 8; ++w) {
            float nm = fmaxf(M0, smred[w][0]);
            L0 = L0 * __expf(M0 - nm) + smred[w][1] * __expf(smred[w][0] - nm);
            M0 = nm;
            nm = fmaxf(M1, smred[w][2]);
            L1 = L1 * __expf(M1 - nm) + smred[w][3] * __expf(smred[w][2] - nm);
            M1 = nm;
        }
        float* sm = ws + WS_SM + (bb * 32 + xx) * 4;
        sm[0] = M0; sm[1] = L0; sm[2] = M1; sm[3] = L1;
    }
}

// ------------------------ fused softmax-finalize + logits partials
// grid 256 x 512 threads: b = bid>>5, x = bid&31.
__global__ void __launch_bounds__(512)
tan_logits_kernel(float* __restrict__ ws, float* __restrict__ out) {
    __shared__ float as4[1024];
    __shared__ float cons[4];
    __shared__ float pacc[512];
    int b = blockIdx.x >> 5;
    int x = blockIdx.x & 31;
    int t = threadIdx.x;
    int k = t & 255;
    int half = t >> 8;
    const float* _zb = ws + WS_Z + b * 8192;
    float zreg[32];
#pragma unroll
    for (int zi = 0; zi < 32; ++zi) zreg[zi] = _zb[zi * 256 + k];

    if (t < 64) {
        const float* sm = ws + WS_SM + (b * 32 + (t & 31)) * 4;
        float4 p = *(const float4*)sm;
        float m0 = p.x, l0 = p.y, m1 = p.z, l1 = p.w;
#pragma unroll
        for (int o = 1; o < 32; o <<= 1) {
            float mo = __shfl_xor(m0, o), lo = __shfl_xor(l0, o);
            float nm = fmaxf(m0, mo);
            l0 = l0 * __expf(m0 - nm) + lo * __expf(mo - nm); m0 = nm;
            mo = __shfl_xor(m1, o); lo = __shfl_xor(l1, o);
            nm = fmaxf(m1, mo);
            l1 = l1 * __expf(m1 - nm) + lo * __expf(mo - nm); m1 = nm;
        }
        if (t == 0) {
            cons[0] = m0; cons[1] = 1.f / l0;
            cons[2] = m1; cons[3] = 1.f / l1;
        }
    }
    __syncthreads();
    float M0 = cons[0], inv0 = cons[1], M1 = cons[2], inv1 = cons[3];
    const float* r0 = ws + WS_RAW + (b * 2) * XYZ + x * 1024;
    const float* r1 = r0 + XYZ;
    float* o0 = out + BB * KK + (b * 2) * XYZ + x * 1024;
    float* o1 = o0 + XYZ;
#pragma unroll
    for (int i = t; i < 1024; i += 512) {
        float a0 = __expf(r0[i] - M0) * inv0;
        float a1 = __expf(r1[i] - M1) * inv1;
        o0[i] = a0; o1[i] = a1;
        as4[i] = a0 + a1;
    }
    __syncthreads();

    const float* _yb = ws + WS_Y + b * 8192;
    float acc = 0.f;
    int y0 = half * 16;
#pragma unroll 4
    for (int yi = 0; yi < 16; ++yi) {
        int yy = y0 + yi;
        float s = 0.f;
        const float4* ar = (const float4*)(as4 + yy * 32);
#pragma unroll
        for (int j = 0; j < 8; ++j) {
            float4 a = ar[j];
            s += a.x * zreg[j * 4] + a.y * zreg[j * 4 + 1]
               + a.z * zreg[j * 4 + 2] + a.w * zreg[j * 4 + 3];
        }
        acc = fmaf(_yb[yy * 256 + k], s, acc);
    }
    pacc[t] = acc;
    __syncthreads();
    if (t < 256) {
        float xv = ws[WS_X + (b * 32 + x) * 256 + t];
        ws[WS_PART + (b * 32 + x) * 256 + t] = xv * (pacc[t] + pacc[t + 256]);
    }
}

// ---------------------------------------------------------------- batchnorm
// 1 block, 1024 threads: tg = t>>8 sums 8 x-slices; LDS combine; tg 0 writes.
__global__ void __launch_bounds__(1024)
tan_bn_kernel(const float* ws, const float* gamma, const float* beta, float* out) {
    __shared__ float red[8192];
    int t = threadIdx.x;
    int tg = t >> 8;
    int k = t & 255;
    const float* part = ws + WS_PART;
    float lg[BB];
#pragma unroll
    for (int b = 0; b < BB; ++b) {
        float s = 0.f;
#pragma unroll
        for (int xi = 0; xi < 8; ++xi)
            s += part[(b * 32 + tg * 8 + xi) * 256 + k];
        red[tg * 2048 + b * 256 + k] = s;
    }
    __syncthreads();
    if (tg == 0) {
#pragma unroll
        for (int b = 0; b < BB; ++b)
            lg[b] = red[b * 256 + k] + red[2048 + b * 256 + k]
                  + red[4096 + b * 256 + k] + red[6144 + b * 256 + k];
        float mean = 0.f;
#pragma unroll
        for (int b = 0; b < BB; ++b) mean += lg[b];
        mean *= 0.125f;
        float var = 0.f;
#pragma unroll
        for (int b = 0; b < BB; ++b) { float d = lg[b] - mean; var += d * d; }
        var *= 0.125f;
        float inv = rsqrtf(var + EPSV);
        float gm = gamma[k], bt = beta[k];
#pragma unroll
        for (int b = 0; b < BB; ++b)
            out[b * 256 + k] = (lg[b] - mean) * inv * gm + bt;
    }
}

extern "C" void kernel_launch(void* const* d_in, const int* in_sizes, int n_in,
                              void* d_out, int out_size, void* d_ws, size_t ws_size,
                              hipStream_t stream) {
    (void)in_sizes; (void)n_in; (void)out_size; (void)ws_size;
    const float* x     = (const float*)d_in[0];
    const float* y     = (const float*)d_in[1];
    const float* z     = (const float*)d_in[2];
    const float* Vx    = (const float*)d_in[3];
    const float* gx    = (const float*)d_in[4];
    const float* bx    = (const float*)d_in[5];
    const float* Vy    = (const float*)d_in[6];
    const float* gy    = (const float*)d_in[7];
    const float* by    = (const float*)d_in[8];
    const float* Vz    = (const float*)d_in[9];
    const float* gz    = (const float*)d_in[10];
    const float* bz    = (const float*)d_in[11];
    const float* Vh    = (const float*)d_in[12];
    const float* gh    = (const float*)d_in[13];
    const float* bh    = (const float*)d_in[14];
    const float* gamma = (const float*)d_in[15];
    const float* beta  = (const float*)d_in[16];
    float* ws  = (float*)d_ws;
    float* out = (float*)d_out;

    tan_projscore_kernel<<<256, 512, 0, stream>>>(x, y, z, Vx, Vy, Vz,
                                                  gx, gy, gz, bx, by, bz,
                                                  Vh, gh, bh, ws);
    tan_logits_kernel<<<256, 512, 0, stream>>>(ws, out);
    tan_bn_kernel<<<1, 1024, 0, stream>>>(ws, gamma, beta, out);
}

// Round 5
// 119.565 us; speedup vs baseline: 2.0262x; 2.0262x over previous
//
#include <hip/hip_runtime.h>
#include <math.h>

#define BB 8
#define DD 128
#define KK 256
#define XYZ 32768
#define EPSV 1e-5f

// ws layout (float offsets)
#define WS_X     0                     // [B*32, 256] = 65536
#define WS_Y     65536
#define WS_Z     131072
#define WS_SM    196608                // [B,32,4] softmax partials (m0,l0,m1,l1)
#define WS_LOG   197632                // [B,256] atomic-accumulated logits = 2048
#define WS_CNT   199680                // ints: [0..7] per-b arrival, [8] BN arrival

// swizzled LDS index for proj tiles: row-major [32][256] with 16B-granule XOR
#define SWZ(row, kk) ((row) * 256 + (((((kk) >> 2) ^ ((row) & 7)) << 2) | ((kk) & 3)))

// ---------------------------------------------------------------- projections
// grid 192: which = bid/64 (0:x 1:y 2:z), 4 rows per block.
// block 0 additionally re-arms the atomic counters / logit accumulator
// (visible to the next dispatch via the kernel-boundary release).
__global__ void __launch_bounds__(256)
tan_proj_kernel(const float* x, const float* y, const float* z,
                const float* Vx, const float* Vy, const float* Vz,
                const float* gx, const float* gy, const float* gz,
                const float* bx, const float* by, const float* bz,
                float* ws) {
    __shared__ float lin[4 * DD];
    __shared__ float wred[4];
    int bid = blockIdx.x;
    int t = threadIdx.x;
    if (bid == 0) {
        for (int i = t; i < 2048; i += 256) ws[WS_LOG + i] = 0.f;
        if (t < 9) ((int*)ws)[WS_CNT + t] = 0;
    }
    int which = bid >> 6;
    int rgrp = bid & 63;
    int r0 = rgrp * 4;
    const float *in, *V, *g, *bias;
    float* outp;
    if (which == 0)      { in = x; V = Vx; g = gx; bias = bx; outp = ws + WS_X; }
    else if (which == 1) { in = y; V = Vy; g = gy; bias = by; outp = ws + WS_Y; }
    else                 { in = z; V = Vz; g = gz; bias = bz; outp = ws + WS_Z; }
    {
        int f0 = t, f1 = t + 256;
        lin[f0] = in[(r0 + (f0 >> 7)) * DD + (f0 & 127)];
        lin[f1] = in[(r0 + (f1 >> 7)) * DD + (f1 & 127)];
    }
    __syncthreads();
    const float4* v4 = (const float4*)(V + t * DD);
    const float4* l4 = (const float4*)lin;
    float a0 = 0.f, a1 = 0.f, a2 = 0.f, a3 = 0.f, ssp = 0.f;
#pragma unroll 8
    for (int d4 = 0; d4 < DD / 4; ++d4) {
        float4 a = v4[d4];
        ssp += a.x * a.x + a.y * a.y + a.z * a.z + a.w * a.w;
        float4 b0 = l4[d4];
        float4 b1 = l4[32 + d4];
        float4 b2 = l4[64 + d4];
        float4 b3 = l4[96 + d4];
        a0 += a.x * b0.x + a.y * b0.y + a.z * b0.z + a.w * b0.w;
        a1 += a.x * b1.x + a.y * b1.y + a.z * b1.z + a.w * b1.w;
        a2 += a.x * b2.x + a.y * b2.y + a.z * b2.z + a.w * b2.w;
        a3 += a.x * b3.x + a.y * b3.y + a.z * b3.z + a.w * b3.w;
    }
#pragma unroll
    for (int o = 32; o > 0; o >>= 1) ssp += __shfl_xor(ssp, o);
    if ((t & 63) == 0) wred[t >> 6] = ssp;
    __syncthreads();
    float ss = wred[0] + wred[1] + wred[2] + wred[3];
    float scale = g[0] * rsqrtf(ss);
    float bv = bias[t];
    outp[(r0 + 0) * KK + t] = fmaxf(a0 * scale + bv, 0.f);
    outp[(r0 + 1) * KK + t] = fmaxf(a1 * scale + bv, 0.f);
    outp[(r0 + 2) * KK + t] = fmaxf(a2 * scale + bv, 0.f);
    outp[(r0 + 3) * KK + t] = fmaxf(a3 * scale + bv, 0.f);
}

// ------------- fused score + softmax + logits + last-block BatchNorm --------
// grid 256 x 512: one block per (b,x). Raw scores stay in registers; y/z/x
// tiles staged once in LDS serve both the score and logits phases.
// Cross-block softmax combine: relaxed device-scope atomics + per-b spin
// (all 256 blocks co-resident; no release fences -> no buffer_wbl2).
__global__ void __launch_bounds__(512)
tan_scorelogits_kernel(const float* __restrict__ Vh, const float* __restrict__ gh,
                       const float* __restrict__ bh,
                       const float* __restrict__ gamma,
                       const float* __restrict__ beta,
                       float* __restrict__ ws, float* __restrict__ out) {
    __shared__ float ys[32 * 256];
    __shared__ float zs[32 * 256];
    __shared__ float as4[1024];
    __shared__ float xsh[256];
    __shared__ float smred[8][4];
    __shared__ float cons[4];
    __shared__ float pacc[512];
    __shared__ float shh;
    __shared__ int islast;
    int t = threadIdx.x;
    int bb = blockIdx.x >> 5;
    int xx = blockIdx.x & 31;
    const float* _xb = ws + WS_X + (bb * 32 + xx) * KK;
    const float* _yb = ws + WS_Y + bb * 8192;
    const float* _zb = ws + WS_Z + bb * 8192;

    if (t < 64) {
        float4 h1 = *(const float4*)(Vh + t * 8);
        float4 h2 = *(const float4*)(Vh + t * 8 + 4);
        float hs = h1.x * h1.x + h1.y * h1.y + h1.z * h1.z + h1.w * h1.w
                 + h2.x * h2.x + h2.y * h2.y + h2.z * h2.z + h2.w * h2.w;
#pragma unroll
        for (int o = 32; o > 0; o >>= 1) hs += __shfl_xor(hs, o);
        if (t == 0) shh = hs;
    }

    // stage y/z (swizzled) + x row
#pragma unroll
    for (int i = 0; i < 4; ++i) {
        int flat = i * 2048 + t * 4;
        int row = flat >> 8;
        int k = flat & 255;
        int gsw = (((k >> 2) ^ (row & 7)) << 2);
        *(float4*)(ys + row * 256 + gsw) = *(const float4*)(_yb + flat);
        *(float4*)(zs + row * 256 + gsw) = *(const float4*)(_zb + flat);
    }
    if (t < 256) xsh[t] = _xb[t];
    __syncthreads();
    float sh = gh[0] * rsqrtf(shh);

    // ---- phase 1: score loop (round-2 structure, scores stay in regs) ----
    int ty = t >> 4;
    int tz = t & 15;
    int z0 = tz, z1 = tz + 16;
    int ysw = (ty & 7);
    int zsw = (tz & 7);

    float s00 = 0.f, s01 = 0.f, s10 = 0.f, s11 = 0.f;

#pragma unroll 4
    for (int kc = 0; kc < 256; kc += 4) {
        int g = kc >> 2;
        float4 xv  = *(const float4*)(xsh + kc);
        float4 vh0 = *(const float4*)(Vh + kc);
        float4 vh1 = *(const float4*)(Vh + KK + kc);
        float4 ya = *(const float4*)(ys + ty * 256 + ((g ^ ysw) << 2));
        float4 za = *(const float4*)(zs + z0 * 256 + ((g ^ zsw) << 2));
        float4 zb = *(const float4*)(zs + z1 * 256 + ((g ^ zsw) << 2));
#define TAN_STEP(c) { \
        float xs = sh * xv.c; \
        float w0 = xs * vh0.c, w1 = xs * vh1.c; \
        float t0 = w0 * ya.c, t1 = w1 * ya.c; \
        s00 = fmaf(t0, za.c, s00); s01 = fmaf(t0, zb.c, s01); \
        s10 = fmaf(t1, za.c, s10); s11 = fmaf(t1, zb.c, s11); }
        TAN_STEP(x) TAN_STEP(y) TAN_STEP(z) TAN_STEP(w)
#undef TAN_STEP
    }

    float b0 = bh[0], b1 = bh[1];
    s00 += b0; s01 += b0;
    s10 += b1; s11 += b1;

    // ---- phase 2: local softmax partials -> publish -> per-b spin ----
    {
        float m0 = fmaxf(s00, s01);
        float l0 = __expf(s00 - m0) + __expf(s01 - m0);
        float m1 = fmaxf(s10, s11);
        float l1 = __expf(s10 - m1) + __expf(s11 - m1);
#pragma unroll
        for (int o = 1; o < 64; o <<= 1) {
            float mo = __shfl_xor(m0, o), lo = __shfl_xor(l0, o);
            float nm = fmaxf(m0, mo);
            l0 = l0 * __expf(m0 - nm) + lo * __expf(mo - nm); m0 = nm;
            mo = __shfl_xor(m1, o); lo = __shfl_xor(l1, o);
            nm = fmaxf(m1, mo);
            l1 = l1 * __expf(m1 - nm) + lo * __expf(mo - nm); m1 = nm;
        }
        if ((t & 63) == 0) {
            int w = t >> 6;
            smred[w][0] = m0; smred[w][1] = l0;
            smred[w][2] = m1; smred[w][3] = l1;
        }
    }
    __syncthreads();
    if (t == 0) {
        float M0 = smred[0][0], L0 = smred[0][1];
        float M1 = smred[0][2], L1 = smred[0][3];
#pragma unroll
        for (int w = 1; w < 8; ++w) {
            float nm = fmaxf(M0, smred[w][0]);
            L0 = L0 * __expf(M0 - nm) + smred[w][1] * __expf(smred[w][0] - nm);
            M0 = nm;
            nm = fmaxf(M1, smred[w][2]);
            L1 = L1 * __expf(M1 - nm) + smred[w][3] * __expf(smred[w][2] - nm);
            M1 = nm;
        }
        float* sm = ws + WS_SM + (bb * 32 + xx) * 4;
        __hip_atomic_store(sm + 0, M0, __ATOMIC_RELAXED, __HIP_MEMORY_SCOPE_AGENT);
        __hip_atomic_store(sm + 1, L0, __ATOMIC_RELAXED, __HIP_MEMORY_SCOPE_AGENT);
        __hip_atomic_store(sm + 2, M1, __ATOMIC_RELAXED, __HIP_MEMORY_SCOPE_AGENT);
        __hip_atomic_store(sm + 3, L1, __ATOMIC_RELAXED, __HIP_MEMORY_SCOPE_AGENT);
        asm volatile("s_waitcnt vmcnt(0)" ::: "memory");   // stores at LLC
        int* cnt = (int*)ws + WS_CNT + bb;
        __hip_atomic_fetch_add(cnt, 1, __ATOMIC_RELAXED, __HIP_MEMORY_SCOPE_AGENT);
        while (__hip_atomic_load(cnt, __ATOMIC_RELAXED, __HIP_MEMORY_SCOPE_AGENT) < 32)
            __builtin_amdgcn_s_sleep(8);
    }
    __syncthreads();

    // reduce the 32 published partials (identical data+order in all siblings)
    if (t < 64) {
        const float* sm = ws + WS_SM + (bb * 32 + (t & 31)) * 4;
        float m0 = __hip_atomic_load(sm + 0, __ATOMIC_RELAXED, __HIP_MEMORY_SCOPE_AGENT);
        float l0 = __hip_atomic_load(sm + 1, __ATOMIC_RELAXED, __HIP_MEMORY_SCOPE_AGENT);
        float m1 = __hip_atomic_load(sm + 2, __ATOMIC_RELAXED, __HIP_MEMORY_SCOPE_AGENT);
        float l1 = __hip_atomic_load(sm + 3, __ATOMIC_RELAXED, __HIP_MEMORY_SCOPE_AGENT);
#pragma unroll
        for (int o = 1; o < 32; o <<= 1) {
            float mo = __shfl_xor(m0, o), lo = __shfl_xor(l0, o);
            float nm = fmaxf(m0, mo);
            l0 = l0 * __expf(m0 - nm) + lo * __expf(mo - nm); m0 = nm;
            mo = __shfl_xor(m1, o); lo = __shfl_xor(l1, o);
            nm = fmaxf(m1, mo);
            l1 = l1 * __expf(m1 - nm) + lo * __expf(mo - nm); m1 = nm;
        }
        if (t == 0) {
            cons[0] = m0; cons[1] = 1.f / l0;
            cons[2] = m1; cons[3] = 1.f / l1;
        }
    }
    __syncthreads();

    // ---- phase 3: finalize att from registers, build as4 ----
    float M0 = cons[0], inv0 = cons[1], M1 = cons[2], inv1 = cons[3];
    float e000 = __expf(s00 - M0) * inv0, e001 = __expf(s01 - M0) * inv0;
    float e100 = __expf(s10 - M1) * inv1, e101 = __expf(s11 - M1) * inv1;

    float* o0 = out + BB * KK + (bb * 2 + 0) * XYZ + xx * 1024;
    float* o1 = o0 + XYZ;
    o0[ty * 32 + z0] = e000;  o0[ty * 32 + z1] = e001;
    o1[ty * 32 + z0] = e100;  o1[ty * 32 + z1] = e101;
    as4[ty * 32 + z0] = e000 + e100;
    as4[ty * 32 + z1] = e001 + e101;
    __syncthreads();

    // ---- phase 4: logits partial from LDS tiles ----
    {
        int k = t & 255;
        int half = t >> 8;
        float zreg[32];
#pragma unroll
        for (int zi = 0; zi < 32; ++zi) zreg[zi] = zs[SWZ(zi, k)];
        float acc = 0.f;
        int y0 = half * 16;
#pragma unroll 4
        for (int yi = 0; yi < 16; ++yi) {
            int yy = y0 + yi;
            float s = 0.f;
            const float4* ar = (const float4*)(as4 + yy * 32);
#pragma unroll
            for (int j = 0; j < 8; ++j) {
                float4 a = ar[j];
                s += a.x * zreg[j * 4] + a.y * zreg[j * 4 + 1]
                   + a.z * zreg[j * 4 + 2] + a.w * zreg[j * 4 + 3];
            }
            acc = fmaf(ys[SWZ(yy, k)], s, acc);
        }
        pacc[t] = acc;
    }
    __syncthreads();
    if (t < 256) {
        float part = xsh[t] * (pacc[t] + pacc[t + 256]);
        __hip_atomic_fetch_add(ws + WS_LOG + bb * 256 + t, part,
                               __ATOMIC_RELAXED, __HIP_MEMORY_SCOPE_AGENT);
    }

    // ---- phase 5: last-block BatchNorm ----
    asm volatile("s_waitcnt vmcnt(0)" ::: "memory");       // adds at LLC
    __syncthreads();
    if (t == 0) {
        int* bncnt = (int*)ws + WS_CNT + 8;
        int old = __hip_atomic_fetch_add(bncnt, 1, __ATOMIC_RELAXED,
                                         __HIP_MEMORY_SCOPE_AGENT);
        islast = (old == 255);
    }
    __syncthreads();
    if (!islast) return;
    if (t < 256) {
        float lg[BB];
#pragma unroll
        for (int bi = 0; bi < BB; ++bi)
            lg[bi] = __hip_atomic_load(ws + WS_LOG + bi * 256 + t,
                                       __ATOMIC_RELAXED, __HIP_MEMORY_SCOPE_AGENT);
        float mean = 0.f;
#pragma unroll
        for (int bi = 0; bi < BB; ++bi) mean += lg[bi];
        mean *= 0.125f;
        float var = 0.f;
#pragma unroll
        for (int bi = 0; bi < BB; ++bi) { float d = lg[bi] - mean; var += d * d; }
        var *= 0.125f;
        float inv = rsqrtf(var + EPSV);
        float gm = gamma[t], bt = beta[t];
#pragma unroll
        for (int bi = 0; bi < BB; ++bi)
            out[bi * 256 + t] = (lg[bi] - mean) * inv * gm + bt;
    }
}

extern "C" void kernel_launch(void* const* d_in, const int* in_sizes, int n_in,
                              void* d_out, int out_size, void* d_ws, size_t ws_size,
                              hipStream_t stream) {
    (void)in_sizes; (void)n_in; (void)out_size; (void)ws_size;
    const float* x     = (const float*)d_in[0];
    const float* y     = (const float*)d_in[1];
    const float* z     = (const float*)d_in[2];
    const float* Vx    = (const float*)d_in[3];
    const float* gx    = (const float*)d_in[4];
    const float* bx    = (const float*)d_in[5];
    const float* Vy    = (const float*)d_in[6];
    const float* gy    = (const float*)d_in[7];
    const float* by    = (const float*)d_in[8];
    const float* Vz    = (const float*)d_in[9];
    const float* gz    = (const float*)d_in[10];
    const float* bz    = (const float*)d_in[11];
    const float* Vh    = (const float*)d_in[12];
    const float* gh    = (const float*)d_in[13];
    const float* bh    = (const float*)d_in[14];
    const float* gamma = (const float*)d_in[15];
    const float* beta  = (const float*)d_in[16];
    float* ws  = (float*)d_ws;
    float* out = (float*)d_out;

    tan_proj_kernel<<<192, 256, 0, stream>>>(x, y, z, Vx, Vy, Vz,
                                             gx, gy, gz, bx, by, bz, ws);
    tan_scorelogits_kernel<<<256, 512, 0, stream>>>(Vh, gh, bh, gamma, beta,
                                                    ws, out);
}